// Round 4
// baseline (1298.005 us; speedup 1.0000x reference)
//
#include <hip/hip_runtime.h>
#include <hip/hip_bf16.h>
#include <cmath>

#define EPSV 1e-5f

typedef short bf16x8 __attribute__((ext_vector_type(8)));
typedef float f32x4 __attribute__((ext_vector_type(4)));

__device__ __forceinline__ unsigned short f2bf(float f) {
  unsigned u = __float_as_uint(f);
  unsigned r = ((u >> 16) & 1u) + 0x7FFFu;   // RTNE
  return (unsigned short)((u + r) >> 16);
}

__device__ __forceinline__ void async16(const void* g, void* l) {
  __builtin_amdgcn_global_load_lds(
      (const __attribute__((address_space(1))) unsigned int*)g,
      (__attribute__((address_space(3))) unsigned int*)l, 16, 0, 0);
}

// ---- prep: weights fp32 -> bf16. w0 re-laid phase-contiguous: k = ph*196 + pair,
// K padded 588 -> 640 (zeros); L0 consumes 19 K32-intervals (608 cols).
__global__ void prep_conv(const float* __restrict__ w0, const float* __restrict__ w1,
                          const float* __restrict__ w2, unsigned short* __restrict__ w0b,
                          unsigned short* __restrict__ w1b, unsigned short* __restrict__ w2b) {
  int idx = blockIdx.x * 256 + threadIdx.x;
  if (idx < 512 * 640) {
    int o = idx / 640, c = idx - o * 640;
    float v = 0.f;
    if (c < 588) { int ph = c / 196, q = c - ph * 196; v = w0[o * 588 + q * 3 + ph]; }
    w0b[idx] = f2bf(v);
    return;
  }
  idx -= 512 * 640;
  if (idx < 384 * 512) { w1b[idx] = f2bf(w1[idx]); return; }
  idx -= 384 * 512;
  if (idx < 256 * 384) { w2b[idx] = f2bf(w2[idx]); }
}

// ---- prep: softmax(weight_mask) -> wm[16][144] ----
__global__ void prep_wm(const float* __restrict__ wmask, float* __restrict__ wm) {
  int g = threadIdx.x >> 6, lane = threadIdx.x & 63;
  const float* row = wmask + g * 144;
  float v0 = row[lane], v1 = row[lane + 64];
  float v2 = (lane < 16) ? row[lane + 128] : -1e30f;
  float m = fmaxf(fmaxf(v0, v1), v2);
  for (int off = 32; off; off >>= 1) m = fmaxf(m, __shfl_xor(m, off));
  float e0 = expf(v0 - m), e1 = expf(v1 - m), e2 = (lane < 16) ? expf(v2 - m) : 0.f;
  float s = e0 + e1 + e2;
  for (int off = 32; off; off >>= 1) s += __shfl_xor(s, off);
  float inv = 1.f / s;
  wm[g * 144 + lane] = e0 * inv;
  wm[g * 144 + lane + 64] = e1 * inv;
  if (lane < 16) wm[g * 144 + lane + 128] = e2 * inv;
}

// ---------------- fused main: 256 thr (4 waves), TM=32, 80 KB LDS, 2 blocks/CU ----
// LDS (bytes):
//  L0 : B0 dbuf 2x32K [0,65536) | feat dbuf 2x2K [65536,69632) | xc [69632,73216)
//       (K-major: B chunk addr = kc*N*16 + n*16; feat = kc*512 + row*16)
//  L0 epi: h0 32K -> [49152,81920)  (B0-buf1 upper + feat + xc, all dead; buf0 live at p=18)
//  L1 : B1 dbuf 2x24K [0,49152) | h0 [49152,81920)
//  L1 epi: h1 24K -> [0,24576)  (dead B1-buf0)
//  L2 : B2 dbuf 2x16K [24576,57344) | h1 [0,24576)
__launch_bounds__(256, 2)
__global__ void fused_main(const float* __restrict__ x, const float* __restrict__ b0,
                           const float* __restrict__ b1, const float* __restrict__ b2,
                           const unsigned short* __restrict__ w0b,
                           const unsigned short* __restrict__ w1b,
                           const unsigned short* __restrict__ w2b,
                           const float* __restrict__ wm, float* __restrict__ out) {
  __shared__ __align__(16) char lds[81920];
  const int tid = threadIdx.x;
  const int wv = tid >> 6, lane = tid & 63;
  const int quad = lane >> 4, l15 = lane & 15;
  const int r0 = blockIdx.x * 32;

  // ---- xc: per-row xi/xj (14 fp32 each), x[:,167] forced 0 ----
  {
    int row = tid >> 3, idx = tid & 7;
    int r = r0 + row;
    int b = r / 144, p = r - b * 144;
    int h = p / 12, w = p - h * 12;
    const float* xb = x + b * 168;
    float* xi = (float*)(lds + 69632u) + row * 14;
    float* xj = (float*)(lds + 71424u) + row * 14;
    for (int ii = idx; ii < 14; ii += 8) {
      int i = ii * 12 + h;
      xi[ii] = (i == 167) ? 0.f : xb[i];
      int j = ii * 12 + w;
      xj[ii] = (j == 167) ? 0.f : xb[j];
    }
  }
  __syncthreads();

  // ---- genF: incremental (ph,i,j) state, advanced +32/interval; no div in loop ----
  const int g_row = (lane >> 1) & 31;          // (tid&63)>>1
  const int k0 = wv * 8 + (tid & 1) * 4;       // 0..28
  int g_ph = 0, g_i = k0 / 14, g_j = k0 - (k0 / 14) * 14;
  const float* gxi = (const float*)(lds + 69632u) + g_row * 14;
  const float* gxj = (const float*)(lds + 71424u) + g_row * 14;
  const unsigned g_waddr = (unsigned)wv * 512u + (unsigned)g_row * 16u + (unsigned)(tid & 1) * 8u;

  auto genF = [&](unsigned fb) {
    float v[4];
    int lph = g_ph, li = g_i, lj = g_j;
#pragma unroll
    for (int e = 0; e < 4; e++) {
      float f = 0.f;
      if (lph < 3) {
        float a = gxi[li], c2 = gxj[lj];
        if (lph == 0) f = c2 - a;
        else {
          float rcp = __builtin_amdgcn_rcpf(a + c2 + EPSV);
          f = (lph == 1) ? (c2 - a) * rcp : c2 * rcp;
        }
      }
      v[e] = f;
      if (++lj == 14) { lj = 0; if (++li == 14) { li = 0; lph++; } }
    }
    __hip_bfloat162 pa = __float22bfloat162_rn(make_float2(v[0], v[1]));
    __hip_bfloat162 pb = __float22bfloat162_rn(make_float2(v[2], v[3]));
    unsigned lo = *(unsigned*)&pa, hi = *(unsigned*)&pb;
    *(unsigned long long*)(lds + fb + g_waddr) =
        (unsigned long long)lo | ((unsigned long long)hi << 32);
    g_i += 2; g_j += 4;
    if (g_j >= 14) { g_j -= 14; g_i++; }
    if (g_i >= 14) { g_i -= 14; g_ph++; }
  };

  // =================== Layer 0 : feat(608) -> 512 ===================
  // stage0 call i: m=i*256+tid -> kc=i>>1, n=(i&1)*256+tid ; dest = m*16 (K-major)
  const char* gB0 = (const char*)w0b + tid * 1280;
  auto stage0 = [&](int p, unsigned bufbase) {
#pragma unroll
    for (int i = 0; i < 8; i++)
      async16(gB0 + ((i & 1) * 256 * 1280 + (i >> 1) * 16 + p * 64),
              lds + bufbase + (unsigned)(i * 4096) + (unsigned)tid * 16u);
  };
  genF(65536u);
  stage0(0, 0u);
  __syncthreads();

  f32x4 acc0[2][8];
#pragma unroll
  for (int a = 0; a < 2; a++)
#pragma unroll
    for (int c = 0; c < 8; c++) acc0[a][c] = f32x4{0.f, 0.f, 0.f, 0.f};

  {
    const unsigned aoff = (unsigned)quad * 512u + (unsigned)l15 * 16u;
    const unsigned boff = (unsigned)quad * 8192u + (unsigned)((wv * 128 + l15) * 16);
    for (int p = 0; p < 19; p++) {
      unsigned bb = (unsigned)(p & 1) * 32768u;
      unsigned fb = 65536u + (unsigned)(p & 1) * 2048u;
      bf16x8 af[2], bfr[8];
#pragma unroll
      for (int rt = 0; rt < 2; rt++)
        af[rt] = *(const bf16x8*)(lds + fb + aoff + (unsigned)(rt * 256));
#pragma unroll
      for (int ct = 0; ct < 8; ct++)
        bfr[ct] = *(const bf16x8*)(lds + bb + boff + (unsigned)(ct * 256));
      if (p + 1 < 19) {
        genF(65536u + (unsigned)((p + 1) & 1) * 2048u);
        stage0(p + 1, (unsigned)((p + 1) & 1) * 32768u);
      }
#pragma unroll
      for (int rt = 0; rt < 2; rt++)
#pragma unroll
        for (int ct = 0; ct < 8; ct++)
          acc0[rt][ct] = __builtin_amdgcn_mfma_f32_16x16x32_bf16(af[rt], bfr[ct], acc0[rt][ct], 0, 0, 0);
      __syncthreads();
    }
  }

  // ---- L1 staging bases (N=384: kc = m/384 via mul-shift) ----
  const char* gB1[6];
#pragma unroll
  for (int i = 0; i < 6; i++) {
    int m = i * 256 + tid;
    int kc = (m * 683) >> 18;
    int n = m - kc * 384;
    gB1[i] = (const char*)w1b + n * 1024 + kc * 16;
  }
  auto stage1 = [&](int p, unsigned bufbase) {
#pragma unroll
    for (int i = 0; i < 6; i++)
      async16(gB1[i] + p * 64, lds + bufbase + (unsigned)(i * 4096) + (unsigned)tid * 16u);
  };
  stage1(0, 0u);

  // ---- h0 epilogue: bias+relu -> bf16, K-major at [49152,81920) ----
#pragma unroll
  for (int ct = 0; ct < 8; ct++) {
    int col = wv * 128 + ct * 16 + l15;
    float bias = b0[col];
    unsigned cbase = 49152u + (unsigned)(col >> 3) * 512u + (unsigned)((col & 7) * 2) + (unsigned)quad * 64u;
#pragma unroll
    for (int rt = 0; rt < 2; rt++)
#pragma unroll
      for (int vi = 0; vi < 4; vi++) {
        float v = fmaxf(acc0[rt][ct][vi] + bias, 0.f);
        *(unsigned short*)(lds + cbase + (unsigned)(rt * 256 + vi * 16)) = f2bf(v);
      }
  }
  __syncthreads();

  // =================== Layer 1 : 512 -> 384 ===================
  f32x4 acc1[2][6];
#pragma unroll
  for (int a = 0; a < 2; a++)
#pragma unroll
    for (int c = 0; c < 6; c++) acc1[a][c] = f32x4{0.f, 0.f, 0.f, 0.f};

  {
    const unsigned aoff = 49152u + (unsigned)quad * 512u + (unsigned)l15 * 16u;
    const unsigned boff = (unsigned)quad * 6144u + (unsigned)((wv * 96 + l15) * 16);
    for (int p = 0; p < 16; p++) {
      unsigned bb = (unsigned)(p & 1) * 24576u;
      bf16x8 af[2], bfr[6];
#pragma unroll
      for (int rt = 0; rt < 2; rt++)
        af[rt] = *(const bf16x8*)(lds + aoff + (unsigned)(p * 2048) + (unsigned)(rt * 256));
#pragma unroll
      for (int ct = 0; ct < 6; ct++)
        bfr[ct] = *(const bf16x8*)(lds + bb + boff + (unsigned)(ct * 256));
      if (p + 1 < 16) stage1(p + 1, (unsigned)((p + 1) & 1) * 24576u);
#pragma unroll
      for (int rt = 0; rt < 2; rt++)
#pragma unroll
        for (int ct = 0; ct < 6; ct++)
          acc1[rt][ct] = __builtin_amdgcn_mfma_f32_16x16x32_bf16(af[rt], bfr[ct], acc1[rt][ct], 0, 0, 0);
      __syncthreads();
    }
  }

  // ---- L2 staging bases (N=256) ----
  const char* gB2[4];
#pragma unroll
  for (int i = 0; i < 4; i++) {
    int m = i * 256 + tid;
    int kc = m >> 8, n = m & 255;
    gB2[i] = (const char*)w2b + n * 768 + kc * 16;
  }
  auto stage2 = [&](int p, unsigned bufbase) {
#pragma unroll
    for (int i = 0; i < 4; i++)
      async16(gB2[i] + p * 64, lds + bufbase + (unsigned)(i * 4096) + (unsigned)tid * 16u);
  };
  stage2(0, 24576u);

  // ---- h1 epilogue -> K-major at [0,24576) ----
#pragma unroll
  for (int ct = 0; ct < 6; ct++) {
    int col = wv * 96 + ct * 16 + l15;
    float bias = b1[col];
    unsigned cbase = (unsigned)(col >> 3) * 512u + (unsigned)((col & 7) * 2) + (unsigned)quad * 64u;
#pragma unroll
    for (int rt = 0; rt < 2; rt++)
#pragma unroll
      for (int vi = 0; vi < 4; vi++) {
        float v = fmaxf(acc1[rt][ct][vi] + bias, 0.f);
        *(unsigned short*)(lds + cbase + (unsigned)(rt * 256 + vi * 16)) = f2bf(v);
      }
  }
  __syncthreads();

  // =================== Layer 2 : 384 -> 256, fused weighted reduction ==============
  f32x4 acc2[2][4];
#pragma unroll
  for (int a = 0; a < 2; a++)
#pragma unroll
    for (int c = 0; c < 4; c++) acc2[a][c] = f32x4{0.f, 0.f, 0.f, 0.f};

  {
    const unsigned aoff = (unsigned)quad * 512u + (unsigned)l15 * 16u;
    const unsigned boff = (unsigned)quad * 4096u + (unsigned)((wv * 64 + l15) * 16);
    for (int p = 0; p < 12; p++) {
      unsigned bb = 24576u + (unsigned)(p & 1) * 16384u;
      bf16x8 af[2], bfr[4];
#pragma unroll
      for (int rt = 0; rt < 2; rt++)
        af[rt] = *(const bf16x8*)(lds + aoff + (unsigned)(p * 2048) + (unsigned)(rt * 256));
#pragma unroll
      for (int ct = 0; ct < 4; ct++)
        bfr[ct] = *(const bf16x8*)(lds + bb + boff + (unsigned)(ct * 256));
      if (p + 1 < 12) stage2(p + 1, 24576u + (unsigned)((p + 1) & 1) * 16384u);
#pragma unroll
      for (int rt = 0; rt < 2; rt++)
#pragma unroll
        for (int ct = 0; ct < 4; ct++)
          acc2[rt][ct] = __builtin_amdgcn_mfma_f32_16x16x32_bf16(af[rt], bfr[ct], acc2[rt][ct], 0, 0, 0);
      __syncthreads();
    }
  }

  // ---- final: relu(h2+b2) * softmax-wm, reduce rows, atomicAdd ----
  {
    int bi = r0 / 144;
    int boundary = (bi + 1) * 144;
#pragma unroll
    for (int ct = 0; ct < 4; ct++) {
      int col = wv * 64 + ct * 16 + l15;
      float bias = b2[col];
      const float* wmg = wm + (col >> 4) * 144;
      float s0 = 0.f, s1 = 0.f;
#pragma unroll
      for (int rt = 0; rt < 2; rt++)
#pragma unroll
        for (int vi = 0; vi < 4; vi++) {
          int r = r0 + rt * 16 + quad * 4 + vi;
          float v = fmaxf(acc2[rt][ct][vi] + bias, 0.f);
          if (r < boundary) s0 += v * wmg[r - bi * 144];
          else              s1 += v * wmg[r - boundary];
        }
      s0 += __shfl_xor(s0, 16); s0 += __shfl_xor(s0, 32);
      s1 += __shfl_xor(s1, 16); s1 += __shfl_xor(s1, 32);
      if (quad == 0) {
        atomicAdd(out + bi * 256 + col, s0);
        if (boundary < r0 + 32) atomicAdd(out + (bi + 1) * 256 + col, s1);
      }
    }
  }
}

extern "C" void kernel_launch(void* const* d_in, const int* in_sizes, int n_in,
                              void* d_out, int out_size, void* d_ws, size_t ws_size,
                              hipStream_t stream) {
  (void)in_sizes; (void)n_in; (void)ws_size;
  const float* x     = (const float*)d_in[0];
  const float* w0    = (const float*)d_in[1];
  const float* b0    = (const float*)d_in[2];
  const float* w1    = (const float*)d_in[3];
  const float* b1    = (const float*)d_in[4];
  const float* w2    = (const float*)d_in[5];
  const float* b2    = (const float*)d_in[6];
  const float* wmask = (const float*)d_in[7];
  float* out = (float*)d_out;
  char* ws = (char*)d_ws;
  float* wm = (float*)ws;                                         // 16*144*4 = 9216
  unsigned short* w0b = (unsigned short*)(ws + 9216);             // 512*640*2 = 655360
  unsigned short* w1b = (unsigned short*)(ws + 9216 + 655360);    // 384*512*2 = 393216
  unsigned short* w2b = (unsigned short*)(ws + 9216 + 655360 + 393216);  // 256*384*2

  hipMemsetAsync(d_out, 0, (size_t)out_size * sizeof(float), stream);
  prep_conv<<<2432, 256, 0, stream>>>(w0, w1, w2, w0b, w1b, w2b);
  prep_wm<<<1, 1024, 0, stream>>>(wmask, wm);
  fused_main<<<4608, 256, 0, stream>>>(x, b0, b1, b2, w0b, w1b, w2b, wm, out);
}

// Round 5
// 432.323 us; speedup vs baseline: 3.0024x; 3.0024x over previous
//
#include <hip/hip_runtime.h>
#include <hip/hip_bf16.h>
#include <cmath>

#define EPSV 1e-5f

typedef short bf16x8 __attribute__((ext_vector_type(8)));
typedef float f32x4 __attribute__((ext_vector_type(4)));

__device__ __forceinline__ unsigned short f2bf(float f) {
  unsigned u = __float_as_uint(f);
  unsigned r = ((u >> 16) & 1u) + 0x7FFFu;   // RTNE
  return (unsigned short)((u + r) >> 16);
}

__device__ __forceinline__ void async16(const void* g, void* l) {
  __builtin_amdgcn_global_load_lds(
      (const __attribute__((address_space(1))) unsigned int*)g,
      (__attribute__((address_space(3))) unsigned int*)l, 16, 0, 0);
}

// ---- prep: weights fp32 -> bf16, TRANSPOSED to K-major chunk layout:
//   wXt[(k>>3)*N + n][8] i.e. 16B chunk index = kc*N + n  (kc = k/8).
// w0 additionally re-laid phase-contiguous in k: k = ph*196 + q, padded 588->640.
// This makes fused_main staging loads perfectly lane-sequential.
__global__ void prep_conv(const float* __restrict__ w0, const float* __restrict__ w1,
                          const float* __restrict__ w2, unsigned short* __restrict__ w0t,
                          unsigned short* __restrict__ w1t, unsigned short* __restrict__ w2t) {
  int idx = blockIdx.x * 256 + threadIdx.x;
  if (idx < 512 * 640) {
    int n = idx / 640, k = idx - n * 640;
    float v = 0.f;
    if (k < 588) { int ph = k / 196, q = k - ph * 196; v = w0[n * 588 + q * 3 + ph]; }
    w0t[(k >> 3) * 4096 + n * 8 + (k & 7)] = f2bf(v);
    return;
  }
  idx -= 512 * 640;
  if (idx < 384 * 512) {
    int n = idx / 512, k = idx - n * 512;
    w1t[(k >> 3) * 3072 + n * 8 + (k & 7)] = f2bf(w1[idx]);
    return;
  }
  idx -= 384 * 512;
  if (idx < 256 * 384) {
    int n = idx / 384, k = idx - n * 384;
    w2t[(k >> 3) * 2048 + n * 8 + (k & 7)] = f2bf(w2[idx]);
  }
}

// ---- prep: softmax(weight_mask) -> wm[16][144] ----
__global__ void prep_wm(const float* __restrict__ wmask, float* __restrict__ wm) {
  int g = threadIdx.x >> 6, lane = threadIdx.x & 63;
  const float* row = wmask + g * 144;
  float v0 = row[lane], v1 = row[lane + 64];
  float v2 = (lane < 16) ? row[lane + 128] : -1e30f;
  float m = fmaxf(fmaxf(v0, v1), v2);
  for (int off = 32; off; off >>= 1) m = fmaxf(m, __shfl_xor(m, off));
  float e0 = expf(v0 - m), e1 = expf(v1 - m), e2 = (lane < 16) ? expf(v2 - m) : 0.f;
  float s = e0 + e1 + e2;
  for (int off = 32; off; off >>= 1) s += __shfl_xor(s, off);
  float inv = 1.f / s;
  wm[g * 144 + lane] = e0 * inv;
  wm[g * 144 + lane + 64] = e1 * inv;
  if (lane < 16) wm[g * 144 + lane + 128] = e2 * inv;
}

// ---------------- fused main: 256 thr (4 waves), TM=32, 80 KB LDS, 2 blocks/CU ----
// LDS (bytes):
//  L0 : B0 dbuf 2x32K [0,65536) | feat dbuf 2x2K [65536,69632) | xc [69632,73216)
//       (K-major: B chunk addr = kc*N*16 + n*16; feat = kc*512 + row*16)
//  L0 epi: h0 32K -> [49152,81920)  (B0-buf1 upper + feat + xc, all dead; buf0 live at p=18)
//  L1 : B1 dbuf 2x24K [0,49152) | h0 [49152,81920)
//  L1 epi: h1 24K -> [0,24576)  (dead B1-buf0)
//  L2 : B2 dbuf 2x16K [24576,57344) | h1 [0,24576)
__launch_bounds__(256, 2)
__global__ void fused_main(const float* __restrict__ x, const float* __restrict__ b0,
                           const float* __restrict__ b1, const float* __restrict__ b2,
                           const unsigned short* __restrict__ w0t,
                           const unsigned short* __restrict__ w1t,
                           const unsigned short* __restrict__ w2t,
                           const float* __restrict__ wm, float* __restrict__ out) {
  __shared__ __align__(16) char lds[81920];
  const int tid = threadIdx.x;
  const int wv = tid >> 6, lane = tid & 63;
  const int quad = lane >> 4, l15 = lane & 15;
  const int r0 = blockIdx.x * 32;

  // ---- xc: per-row xi/xj (14 fp32 each), x[:,167] forced 0 ----
  {
    int row = tid >> 3, idx = tid & 7;
    int r = r0 + row;
    int b = r / 144, p = r - b * 144;
    int h = p / 12, w = p - h * 12;
    const float* xb = x + b * 168;
    float* xi = (float*)(lds + 69632u) + row * 14;
    float* xj = (float*)(lds + 71424u) + row * 14;
    for (int ii = idx; ii < 14; ii += 8) {
      int i = ii * 12 + h;
      xi[ii] = (i == 167) ? 0.f : xb[i];
      int j = ii * 12 + w;
      xj[ii] = (j == 167) ? 0.f : xb[j];
    }
  }
  __syncthreads();

  // ---- genF: incremental (ph,i,j) state, advanced +32/interval; no div in loop ----
  const int g_row = (lane >> 1) & 31;          // (tid&63)>>1
  const int k0 = wv * 8 + (tid & 1) * 4;       // 0..28
  int g_ph = 0, g_i = k0 / 14, g_j = k0 - (k0 / 14) * 14;
  const float* gxi = (const float*)(lds + 69632u) + g_row * 14;
  const float* gxj = (const float*)(lds + 71424u) + g_row * 14;
  const unsigned g_waddr = (unsigned)wv * 512u + (unsigned)g_row * 16u + (unsigned)(tid & 1) * 8u;

  auto genF = [&](unsigned fb) {
    float v[4];
    int lph = g_ph, li = g_i, lj = g_j;
#pragma unroll
    for (int e = 0; e < 4; e++) {
      float f = 0.f;
      if (lph < 3) {
        float a = gxi[li], c2 = gxj[lj];
        if (lph == 0) f = c2 - a;
        else {
          float rcp = __builtin_amdgcn_rcpf(a + c2 + EPSV);
          f = (lph == 1) ? (c2 - a) * rcp : c2 * rcp;
        }
      }
      v[e] = f;
      if (++lj == 14) { lj = 0; if (++li == 14) { li = 0; lph++; } }
    }
    __hip_bfloat162 pa = __float22bfloat162_rn(make_float2(v[0], v[1]));
    __hip_bfloat162 pb = __float22bfloat162_rn(make_float2(v[2], v[3]));
    unsigned lo = *(unsigned*)&pa, hi = *(unsigned*)&pb;
    *(unsigned long long*)(lds + fb + g_waddr) =
        (unsigned long long)lo | ((unsigned long long)hi << 32);
    g_i += 2; g_j += 4;
    if (g_j >= 14) { g_j -= 14; g_i++; }
    if (g_i >= 14) { g_i -= 14; g_ph++; }
  };

  // =================== Layer 0 : feat(608) -> 512 ===================
  // K-major source: chunk = p*2048 + i*256 + tid  -> lane-sequential 16B loads.
  const char* gB0 = (const char*)w0t + tid * 16;
  auto stage0 = [&](int p, unsigned bufbase) {
    const char* s = gB0 + p * 32768;
#pragma unroll
    for (int i = 0; i < 8; i++)
      async16(s + i * 4096, lds + bufbase + (unsigned)(i * 4096) + (unsigned)tid * 16u);
  };
  genF(65536u);
  stage0(0, 0u);
  __syncthreads();

  f32x4 acc0[2][8];
#pragma unroll
  for (int a = 0; a < 2; a++)
#pragma unroll
    for (int c = 0; c < 8; c++) acc0[a][c] = f32x4{0.f, 0.f, 0.f, 0.f};

  {
    const unsigned aoff = (unsigned)quad * 512u + (unsigned)l15 * 16u;
    const unsigned boff = (unsigned)quad * 8192u + (unsigned)((wv * 128 + l15) * 16);
    for (int p = 0; p < 19; p++) {
      unsigned bb = (unsigned)(p & 1) * 32768u;
      unsigned fb = 65536u + (unsigned)(p & 1) * 2048u;
      bf16x8 af[2], bfr[8];
#pragma unroll
      for (int rt = 0; rt < 2; rt++)
        af[rt] = *(const bf16x8*)(lds + fb + aoff + (unsigned)(rt * 256));
#pragma unroll
      for (int ct = 0; ct < 8; ct++)
        bfr[ct] = *(const bf16x8*)(lds + bb + boff + (unsigned)(ct * 256));
      if (p + 1 < 19) {
        genF(65536u + (unsigned)((p + 1) & 1) * 2048u);
        stage0(p + 1, (unsigned)((p + 1) & 1) * 32768u);
      }
#pragma unroll
      for (int rt = 0; rt < 2; rt++)
#pragma unroll
        for (int ct = 0; ct < 8; ct++)
          acc0[rt][ct] = __builtin_amdgcn_mfma_f32_16x16x32_bf16(af[rt], bfr[ct], acc0[rt][ct], 0, 0, 0);
      __syncthreads();
    }
  }

  // ---- L1 staging (K-major, lane-sequential) ----
  const char* gB1 = (const char*)w1t + tid * 16;
  auto stage1 = [&](int p, unsigned bufbase) {
    const char* s = gB1 + p * 24576;
#pragma unroll
    for (int i = 0; i < 6; i++)
      async16(s + i * 4096, lds + bufbase + (unsigned)(i * 4096) + (unsigned)tid * 16u);
  };
  stage1(0, 0u);

  // ---- h0 epilogue: bias+relu -> bf16, K-major at [49152,81920) ----
#pragma unroll
  for (int ct = 0; ct < 8; ct++) {
    int col = wv * 128 + ct * 16 + l15;
    float bias = b0[col];
    unsigned cbase = 49152u + (unsigned)(col >> 3) * 512u + (unsigned)((col & 7) * 2) + (unsigned)quad * 64u;
#pragma unroll
    for (int rt = 0; rt < 2; rt++)
#pragma unroll
      for (int vi = 0; vi < 4; vi++) {
        float v = fmaxf(acc0[rt][ct][vi] + bias, 0.f);
        *(unsigned short*)(lds + cbase + (unsigned)(rt * 256 + vi * 16)) = f2bf(v);
      }
  }
  __syncthreads();

  // =================== Layer 1 : 512 -> 384 ===================
  f32x4 acc1[2][6];
#pragma unroll
  for (int a = 0; a < 2; a++)
#pragma unroll
    for (int c = 0; c < 6; c++) acc1[a][c] = f32x4{0.f, 0.f, 0.f, 0.f};

  {
    const unsigned aoff = 49152u + (unsigned)quad * 512u + (unsigned)l15 * 16u;
    const unsigned boff = (unsigned)quad * 6144u + (unsigned)((wv * 96 + l15) * 16);
    for (int p = 0; p < 16; p++) {
      unsigned bb = (unsigned)(p & 1) * 24576u;
      bf16x8 af[2], bfr[6];
#pragma unroll
      for (int rt = 0; rt < 2; rt++)
        af[rt] = *(const bf16x8*)(lds + aoff + (unsigned)(p * 2048) + (unsigned)(rt * 256));
#pragma unroll
      for (int ct = 0; ct < 6; ct++)
        bfr[ct] = *(const bf16x8*)(lds + bb + boff + (unsigned)(ct * 256));
      if (p + 1 < 16) stage1(p + 1, (unsigned)((p + 1) & 1) * 24576u);
#pragma unroll
      for (int rt = 0; rt < 2; rt++)
#pragma unroll
        for (int ct = 0; ct < 6; ct++)
          acc1[rt][ct] = __builtin_amdgcn_mfma_f32_16x16x32_bf16(af[rt], bfr[ct], acc1[rt][ct], 0, 0, 0);
      __syncthreads();
    }
  }

  // ---- L2 staging (K-major, lane-sequential) ----
  const char* gB2 = (const char*)w2t + tid * 16;
  auto stage2 = [&](int p, unsigned bufbase) {
    const char* s = gB2 + p * 16384;
#pragma unroll
    for (int i = 0; i < 4; i++)
      async16(s + i * 4096, lds + bufbase + (unsigned)(i * 4096) + (unsigned)tid * 16u);
  };
  stage2(0, 24576u);

  // ---- h1 epilogue -> K-major at [0,24576) ----
#pragma unroll
  for (int ct = 0; ct < 6; ct++) {
    int col = wv * 96 + ct * 16 + l15;
    float bias = b1[col];
    unsigned cbase = (unsigned)(col >> 3) * 512u + (unsigned)((col & 7) * 2) + (unsigned)quad * 64u;
#pragma unroll
    for (int rt = 0; rt < 2; rt++)
#pragma unroll
      for (int vi = 0; vi < 4; vi++) {
        float v = fmaxf(acc1[rt][ct][vi] + bias, 0.f);
        *(unsigned short*)(lds + cbase + (unsigned)(rt * 256 + vi * 16)) = f2bf(v);
      }
  }
  __syncthreads();

  // =================== Layer 2 : 384 -> 256, fused weighted reduction ==============
  f32x4 acc2[2][4];
#pragma unroll
  for (int a = 0; a < 2; a++)
#pragma unroll
    for (int c = 0; c < 4; c++) acc2[a][c] = f32x4{0.f, 0.f, 0.f, 0.f};

  {
    const unsigned aoff = (unsigned)quad * 512u + (unsigned)l15 * 16u;
    const unsigned boff = (unsigned)quad * 4096u + (unsigned)((wv * 64 + l15) * 16);
    for (int p = 0; p < 12; p++) {
      unsigned bb = 24576u + (unsigned)(p & 1) * 16384u;
      bf16x8 af[2], bfr[4];
#pragma unroll
      for (int rt = 0; rt < 2; rt++)
        af[rt] = *(const bf16x8*)(lds + aoff + (unsigned)(p * 2048) + (unsigned)(rt * 256));
#pragma unroll
      for (int ct = 0; ct < 4; ct++)
        bfr[ct] = *(const bf16x8*)(lds + bb + boff + (unsigned)(ct * 256));
      if (p + 1 < 12) stage2(p + 1, 24576u + (unsigned)((p + 1) & 1) * 16384u);
#pragma unroll
      for (int rt = 0; rt < 2; rt++)
#pragma unroll
        for (int ct = 0; ct < 4; ct++)
          acc2[rt][ct] = __builtin_amdgcn_mfma_f32_16x16x32_bf16(af[rt], bfr[ct], acc2[rt][ct], 0, 0, 0);
      __syncthreads();
    }
  }

  // ---- final: relu(h2+b2) * softmax-wm, reduce rows, atomicAdd ----
  {
    int bi = r0 / 144;
    int boundary = (bi + 1) * 144;
#pragma unroll
    for (int ct = 0; ct < 4; ct++) {
      int col = wv * 64 + ct * 16 + l15;
      float bias = b2[col];
      const float* wmg = wm + (col >> 4) * 144;
      float s0 = 0.f, s1 = 0.f;
#pragma unroll
      for (int rt = 0; rt < 2; rt++)
#pragma unroll
        for (int vi = 0; vi < 4; vi++) {
          int r = r0 + rt * 16 + quad * 4 + vi;
          float v = fmaxf(acc2[rt][ct][vi] + bias, 0.f);
          if (r < boundary) s0 += v * wmg[r - bi * 144];
          else              s1 += v * wmg[r - boundary];
        }
      s0 += __shfl_xor(s0, 16); s0 += __shfl_xor(s0, 32);
      s1 += __shfl_xor(s1, 16); s1 += __shfl_xor(s1, 32);
      if (quad == 0) {
        atomicAdd(out + bi * 256 + col, s0);
        if (boundary < r0 + 32) atomicAdd(out + (bi + 1) * 256 + col, s1);
      }
    }
  }
}

extern "C" void kernel_launch(void* const* d_in, const int* in_sizes, int n_in,
                              void* d_out, int out_size, void* d_ws, size_t ws_size,
                              hipStream_t stream) {
  (void)in_sizes; (void)n_in; (void)ws_size;
  const float* x     = (const float*)d_in[0];
  const float* w0    = (const float*)d_in[1];
  const float* b0    = (const float*)d_in[2];
  const float* w1    = (const float*)d_in[3];
  const float* b1    = (const float*)d_in[4];
  const float* w2    = (const float*)d_in[5];
  const float* b2    = (const float*)d_in[6];
  const float* wmask = (const float*)d_in[7];
  float* out = (float*)d_out;
  char* ws = (char*)d_ws;
  float* wm = (float*)ws;                                         // 16*144*4 = 9216
  unsigned short* w0t = (unsigned short*)(ws + 9216);             // 512*640*2 = 655360
  unsigned short* w1t = (unsigned short*)(ws + 9216 + 655360);    // 384*512*2 = 393216
  unsigned short* w2t = (unsigned short*)(ws + 9216 + 655360 + 393216);  // 256*384*2

  hipMemsetAsync(d_out, 0, (size_t)out_size * sizeof(float), stream);
  prep_conv<<<2432, 256, 0, stream>>>(w0, w1, w2, w0t, w1t, w2t);
  prep_wm<<<1, 1024, 0, stream>>>(wmask, wm);
  fused_main<<<4608, 256, 0, stream>>>(x, b0, b1, b2, w0t, w1t, w2t, wm, out);
}